// Round 2
// baseline (934.036 us; speedup 1.0000x reference)
//
#include <hip/hip_runtime.h>

#define CONF_THRESHOLD 0.01f
#define LOC_VAR 0.1f
#define SIZE_VAR 0.2f

// Single fused kernel.
// Output layout (flat in d_out, floats):
//   [0, R*4)          : decoded boxes, R = B*NA rows of float4
//   [R*4, R*4 + R*81) : indicator (0.0/1.0), R rows of 81
// Thread t:
//   - writes conf quad t (4 consecutive indicator elems, one float4 store)
//   - if t < R, also writes box t (one float4 store)
__global__ __launch_bounds__(256) void infbox_fused(
    const float* __restrict__ pred,     // [R, 85]
    const float4* __restrict__ dboxes,  // [NA] float4 priors
    float* __restrict__ out,
    int NA, unsigned int R, unsigned int M /* R*81 */, unsigned int T) {
    unsigned int t = blockIdx.x * blockDim.x + threadIdx.x;
    if (t >= T) return;

    // ---- indicator quad ----
    unsigned int j = t * 4u;
    if (j < M) {
        unsigned int a = j / 81u;        // row index
        unsigned int c = j - a * 81u;    // class index 0..80
        float r[4];
#pragma unroll
        for (int k = 0; k < 4; ++k) {
            unsigned int jj = j + (unsigned int)k;
            float v = (jj < M) ? pred[(size_t)a * 85u + 4u + c] : 0.0f;
            r[k] = (v > CONF_THRESHOLD) ? 1.0f : 0.0f;
            if (++c == 81u) { c = 0u; ++a; }
        }
        float4* out2 = (float4*)(out + (size_t)R * 4u);
        float4 o2;
        o2.x = r[0]; o2.y = r[1]; o2.z = r[2]; o2.w = r[3];
        out2[t] = o2;
    }

    // ---- box row ----
    if (t < R) {
        size_t base = (size_t)t * 85u;
        float l0 = pred[base + 0];
        float l1 = pred[base + 1];
        float l2 = pred[base + 2];
        float l3 = pred[base + 3];
        float4 db = dboxes[t % (unsigned int)NA];
        float cx = db.x + l0 * LOC_VAR * db.z;
        float cy = db.y + l1 * LOC_VAR * db.w;
        float w  = db.z * expf(l2 * SIZE_VAR);
        float h  = db.w * expf(l3 * SIZE_VAR);
        float4 o1;
        o1.x = cx - w * 0.5f;
        o1.y = cy - h * 0.5f;
        o1.z = cx + w * 0.5f;
        o1.w = cy + h * 0.5f;
        ((float4*)out)[t] = o1;
    }
}

extern "C" void kernel_launch(void* const* d_in, const int* in_sizes, int n_in,
                              void* d_out, int out_size, void* d_ws, size_t ws_size,
                              hipStream_t stream) {
    const float* predicts = (const float*)d_in[0];
    const float* dboxes   = (const float*)d_in[1];
    float* out = (float*)d_out;

    const int NA = in_sizes[1] / 4;                     // 24564
    const unsigned int R = (unsigned int)(out_size / 85); // B*NA rows
    const unsigned int M = R * 81u;                      // indicator elems
    const unsigned int quads = (M + 3u) / 4u;
    const unsigned int T = (quads > R) ? quads : R;

    const int block = 256;
    unsigned int grid = (T + (unsigned int)block - 1u) / (unsigned int)block;
    infbox_fused<<<grid, block, 0, stream>>>(predicts, (const float4*)dboxes,
                                             out, NA, R, M, T);
}